// Round 1
// baseline (5736.690 us; speedup 1.0000x reference)
//
#include <hip/hip_runtime.h>
#include <hip/hip_bf16.h>

#define NN 100000
#define FIN 1024
#define NH 8
#define ND 16
#define NC 128
#define NE 600000
#define NP 3
#define NOUT 3

typedef __attribute__((ext_vector_type(8))) short bf16x8;
typedef __attribute__((ext_vector_type(4))) float f32x4;

__device__ __forceinline__ unsigned short f2bf(float f){
  union { __hip_bfloat16 b; unsigned short u; } cv;
  cv.b = __float2bfloat16(f);
  return cv.u;
}
__device__ __forceinline__ float bf2f(__hip_bfloat16 b){ return __bfloat162float(b); }
__device__ __forceinline__ float tanh_fast(float x){
  float e = __expf(2.0f*x);
  return 1.0f - 2.0f/(e + 1.0f);
}
__device__ __forceinline__ float lrelu(float x){ return x > 0.0f ? x : 0.2f*x; }

// ---------------------------------------------------------------- W transpose + bf16 cast
__global__ __launch_bounds__(256) void k_transpose_w(const float* __restrict__ W,
                                                     __hip_bfloat16* __restrict__ Wt){
  int t = blockIdx.x*256 + threadIdx.x;
  if (t >= FIN*NC) return;
  int k = t >> 7, c = t & 127;
  Wt[(size_t)c*FIN + k] = __float2bfloat16(W[t]);
}

// ---------------------------------------------------------------- h = x @ W + b   (bf16 MFMA)
// block: 256 thr = 4 waves; 64 rows x 128 cols per block; K loop step 32.
__global__ __launch_bounds__(256) void k_proj(const float* __restrict__ x,
                                              const __hip_bfloat16* __restrict__ Wt,
                                              const float* __restrict__ bias,
                                              __hip_bfloat16* __restrict__ h){
  __shared__ __align__(16) __hip_bfloat16 As[64*40];   // pad 40: 2-way LDS conflicts only (free)
  __shared__ __align__(16) __hip_bfloat16 Bs[128*40];
  const int tid = threadIdx.x;
  const int wave = tid >> 6, lane = tid & 63;
  const int lr = lane & 15, lq = lane >> 4;
  const int m0 = blockIdx.x * 64;
  f32x4 acc[8] = {};
  for (int k0 = 0; k0 < FIN; k0 += 32){
    // stage A: x[m0..m0+64][k0..k0+32] fp32 -> bf16 LDS
#pragma unroll
    for (int i=0;i<2;i++){
      int idx = tid + 256*i;           // 0..511
      int row = idx >> 3, f4 = idx & 7;
      int gm = m0 + row; if (gm >= NN) gm = NN-1;
      const float4 v = *reinterpret_cast<const float4*>(x + (size_t)gm*FIN + k0 + f4*4);
      ushort4 pk; pk.x=f2bf(v.x); pk.y=f2bf(v.y); pk.z=f2bf(v.z); pk.w=f2bf(v.w);
      *reinterpret_cast<ushort4*>(&As[row*40 + f4*4]) = pk;
    }
    // stage B^T: Wt[c][k0..k0+32] bf16 -> LDS (16B vector copies)
#pragma unroll
    for (int i=0;i<2;i++){
      int idx = tid + 256*i;           // 0..511
      int c = idx >> 2, q = idx & 3;
      const uint4 v = *reinterpret_cast<const uint4*>(Wt + (size_t)c*FIN + k0 + q*8);
      *reinterpret_cast<uint4*>(&Bs[c*40 + q*8]) = v;
    }
    __syncthreads();
    bf16x8 afr = *reinterpret_cast<const bf16x8*>(&As[(wave*16 + lr)*40 + lq*8]);
#pragma unroll
    for (int t=0;t<8;t++){
      bf16x8 bfr = *reinterpret_cast<const bf16x8*>(&Bs[(t*16 + lr)*40 + lq*8]);
      acc[t] = __builtin_amdgcn_mfma_f32_16x16x32_bf16(afr, bfr, acc[t], 0, 0, 0);
    }
    __syncthreads();
  }
  // epilogue: D lane map col=lane&15, row=(lane>>4)*4+r
#pragma unroll
  for (int t=0;t<8;t++){
    int col = t*16 + lr;
    float bv = bias[col];
#pragma unroll
    for (int r=0;r<4;r++){
      int gm = m0 + wave*16 + lq*4 + r;
      if (gm < NN) h[(size_t)gm*NC + col] = __float2bfloat16(acc[t][r] + bv);
    }
  }
}

// ---------------------------------------------------------------- per-(node,head) attention logits
__global__ __launch_bounds__(256) void k_al(const __hip_bfloat16* __restrict__ h,
      const float* __restrict__ a_src, const float* __restrict__ a_dst,
      float* __restrict__ al_s, float* __restrict__ al_d){
  int t = blockIdx.x*256 + threadIdx.x;
  if (t >= NN*NH) return;
  int n = t >> 3, hh = t & 7;
  const __hip_bfloat16* hp = h + (size_t)n*NC + hh*ND;
  float hv[ND];
#pragma unroll
  for (int d=0; d<ND; d++) hv[d] = bf2f(hp[d]);
#pragma unroll
  for (int p=0;p<NP;p++){
    const float* as = a_src + (p*NH + hh)*ND;
    const float* ad = a_dst + (p*NH + hh)*ND;
    float ss=0.f, sd=0.f;
#pragma unroll
    for (int d=0;d<ND;d++){ ss += hv[d]*as[d]; sd += hv[d]*ad[d]; }
    al_s[((size_t)p*NN + n)*NH + hh] = ss;
    al_d[((size_t)p*NN + n)*NH + hh] = sd;
  }
}

// ---------------------------------------------------------------- softmax denominator (no max-sub needed: |e|<=~11)
__global__ __launch_bounds__(256) void k_denom(const int* __restrict__ edge,
      const float* __restrict__ al_s, const float* __restrict__ al_d,
      float* __restrict__ denom){
  int p = blockIdx.y;
  int idx = blockIdx.x*256 + threadIdx.x;
  int e = idx >> 3, hh = idx & 7;
  if (e >= NE) return;
  int src = edge[(size_t)p*2*NE + e];
  int dst = edge[(size_t)p*2*NE + NE + e];
  float ev = al_s[((size_t)p*NN + src)*NH + hh] + al_d[((size_t)p*NN + dst)*NH + hh];
  atomicAdd(&denom[((size_t)p*NN + dst)*NH + hh], __expf(lrelu(ev)));
}

// ---------------------------------------------------------------- weighted message scatter
__global__ __launch_bounds__(256) void k_scatter(const int* __restrict__ edge,
      const float* __restrict__ al_s, const float* __restrict__ al_d,
      const float* __restrict__ denom, const __hip_bfloat16* __restrict__ h,
      float* __restrict__ outs){
  int p = blockIdx.y;
  int idx = blockIdx.x*256 + threadIdx.x;
  int e = idx >> 7, c = idx & 127;
  int hh = c >> 4;
  int src = edge[(size_t)p*2*NE + e];
  int dst = edge[(size_t)p*2*NE + NE + e];
  size_t di = ((size_t)p*NN + dst)*NH + hh;
  float ev = al_s[((size_t)p*NN + src)*NH + hh] + al_d[di];
  float alpha = __expf(lrelu(ev)) / (denom[di] + 1e-16f);
  float hv = bf2f(h[(size_t)src*NC + c]);
  atomicAdd(&outs[((size_t)p*NN + dst)*NC + c], alpha*hv);
}

// ---------------------------------------------------------------- semantic att: wsum[p,c] = sum_n tanh(relu(outs)@kW + kb)
__global__ __launch_bounds__(256) void k_semantic(const float* __restrict__ outs,
      const float* __restrict__ kW, const float* __restrict__ kb,
      float* __restrict__ wsum){
  __shared__ __align__(16) __hip_bfloat16 As[64*40];
  __shared__ __align__(16) __hip_bfloat16 Bs[128*136];  // whole kW^T, bf16, pad 136
  const int tid = threadIdx.x;
  const int wave = tid >> 6, lane = tid & 63;
  const int lr = lane & 15, lq = lane >> 4;
  const int p = blockIdx.y;
  const int m0 = blockIdx.x*64;
  const float* op = outs + (size_t)p*NN*NC;
  for (int i=tid; i<NC*NC; i+=256){
    int k = i >> 7, c = i & 127;
    Bs[c*136 + k] = __float2bfloat16(kW[i]);
  }
  f32x4 acc[8] = {};
  for (int k0=0; k0<NC; k0+=32){
#pragma unroll
    for (int i=0;i<2;i++){
      int idx = tid + 256*i;
      int row = idx >> 3, f4 = idx & 7;
      int gm = m0 + row; if (gm >= NN) gm = NN-1;
      float4 v = *reinterpret_cast<const float4*>(op + (size_t)gm*NC + k0 + f4*4);
      ushort4 pk;
      pk.x=f2bf(fmaxf(v.x,0.f)); pk.y=f2bf(fmaxf(v.y,0.f));
      pk.z=f2bf(fmaxf(v.z,0.f)); pk.w=f2bf(fmaxf(v.w,0.f));
      *reinterpret_cast<ushort4*>(&As[row*40 + f4*4]) = pk;
    }
    __syncthreads();   // also covers the one-time Bs staging on first iter
    bf16x8 afr = *reinterpret_cast<const bf16x8*>(&As[(wave*16 + lr)*40 + lq*8]);
#pragma unroll
    for (int t=0;t<8;t++){
      bf16x8 bfr = *reinterpret_cast<const bf16x8*>(&Bs[(t*16 + lr)*136 + k0 + lq*8]);
      acc[t] = __builtin_amdgcn_mfma_f32_16x16x32_bf16(afr, bfr, acc[t], 0, 0, 0);
    }
    __syncthreads();
  }
#pragma unroll
  for (int t=0;t<8;t++){
    int col = t*16 + lr;
    float kbv = kb[col];
    float ps = 0.f;
#pragma unroll
    for (int r=0;r<4;r++){
      int gm = m0 + wave*16 + lq*4 + r;
      if (gm < NN) ps += tanh_fast(acc[t][r] + kbv);
    }
    atomicAdd(&wsum[p*NC + col], ps);
  }
}

// ---------------------------------------------------------------- beta = softmax(q . mean_tanh)
__global__ void k_beta(const float* __restrict__ wsum, const float* __restrict__ qv,
                       float* __restrict__ beta){
  int lane = threadIdx.x;  // 64 threads
  float s[NP];
#pragma unroll
  for (int p=0;p<NP;p++){
    float acc = wsum[p*NC + lane]*qv[lane] + wsum[p*NC + lane + 64]*qv[lane + 64];
#pragma unroll
    for (int off=32; off>0; off>>=1) acc += __shfl_down(acc, off);
    s[p] = acc;
  }
  if (lane == 0){
    float sc0 = s[0]/(float)NN, sc1 = s[1]/(float)NN, sc2 = s[2]/(float)NN;
    float mx = fmaxf(sc0, fmaxf(sc1, sc2));
    float e0 = __expf(sc0-mx), e1 = __expf(sc1-mx), e2 = __expf(sc2-mx);
    float inv = 1.0f/(e0+e1+e2);
    beta[0]=e0*inv; beta[1]=e1*inv; beta[2]=e2*inv;
  }
}

// ---------------------------------------------------------------- fused = sum_p beta_p relu(outs_p); out = fused@linW + linb
__global__ __launch_bounds__(256) void k_fuse(const float* __restrict__ outs,
      const float* __restrict__ beta, const float* __restrict__ linW,
      const float* __restrict__ linb, float* __restrict__ out){
  int node = blockIdx.x*4 + (threadIdx.x >> 6);
  int lane = threadIdx.x & 63;
  if (node >= NN) return;
  float b0 = beta[0], b1 = beta[1], b2 = beta[2];
  float a0=0.f, a1=0.f, a2=0.f;
#pragma unroll
  for (int i=0;i<2;i++){
    int c = lane + i*64;
    float f = b0*fmaxf(outs[((size_t)0*NN + node)*NC + c], 0.f)
            + b1*fmaxf(outs[((size_t)1*NN + node)*NC + c], 0.f)
            + b2*fmaxf(outs[((size_t)2*NN + node)*NC + c], 0.f);
    a0 += f*linW[c*NOUT + 0];
    a1 += f*linW[c*NOUT + 1];
    a2 += f*linW[c*NOUT + 2];
  }
#pragma unroll
  for (int off=32; off>0; off>>=1){
    a0 += __shfl_down(a0, off);
    a1 += __shfl_down(a1, off);
    a2 += __shfl_down(a2, off);
  }
  if (lane == 0){
    out[(size_t)node*NOUT + 0] = a0 + linb[0];
    out[(size_t)node*NOUT + 1] = a1 + linb[1];
    out[(size_t)node*NOUT + 2] = a2 + linb[2];
  }
}

extern "C" void kernel_launch(void* const* d_in, const int* in_sizes, int n_in,
                              void* d_out, int out_size, void* d_ws, size_t ws_size,
                              hipStream_t stream){
  const float* x     = (const float*)d_in[0];
  const int*   edge  = (const int*)d_in[1];
  const float* Wp    = (const float*)d_in[2];
  const float* bp    = (const float*)d_in[3];
  const float* a_src = (const float*)d_in[4];
  const float* a_dst = (const float*)d_in[5];
  const float* kW    = (const float*)d_in[6];
  const float* kb    = (const float*)d_in[7];
  const float* qv    = (const float*)d_in[8];
  const float* linW  = (const float*)d_in[9];
  const float* linb  = (const float*)d_in[10];
  float* out = (float*)d_out;
  char* ws = (char*)d_ws;

  // workspace layout (bytes), total ~208.3 MB
  __hip_bfloat16* Wt   = (__hip_bfloat16*)(ws + 0);          //   262,144
  __hip_bfloat16* h    = (__hip_bfloat16*)(ws + 262144);     //  25,600,000
  float* al_s  = (float*)(ws + 25862144);                    //   9,600,000
  float* al_d  = (float*)(ws + 35462144);                    //   9,600,000
  float* denom = (float*)(ws + 45062144);                    //   9,600,000
  float* outs  = (float*)(ws + 54662144);                    // 153,600,000
  float* wsum  = (float*)(ws + 208262144);                   //       1,536
  float* beta  = (float*)(ws + 208263680);                   //          12

  hipMemsetAsync(denom, 0, (size_t)NP*NN*NH*4, stream);
  hipMemsetAsync(outs,  0, (size_t)NP*NN*NC*4, stream);
  hipMemsetAsync(wsum,  0, NP*NC*4, stream);

  k_transpose_w<<<(FIN*NC + 255)/256, 256, 0, stream>>>(Wp, Wt);
  k_proj<<<(NN + 63)/64, 256, 0, stream>>>(x, Wt, bp, h);
  k_al<<<(NN*NH + 255)/256, 256, 0, stream>>>(h, a_src, a_dst, al_s, al_d);
  k_denom<<<dim3(NE*NH/256, NP), 256, 0, stream>>>(edge, al_s, al_d, denom);
  k_scatter<<<dim3(NE*NC/256, NP), 256, 0, stream>>>(edge, al_s, al_d, denom, h, outs);
  k_semantic<<<dim3((NN + 63)/64, NP), 256, 0, stream>>>(outs, kW, kb, wsum);
  k_beta<<<1, 64, 0, stream>>>(wsum, qv, beta);
  k_fuse<<<(NN + 3)/4, 256, 0, stream>>>(outs, beta, linW, linb, out);
}

// Round 2
// 1646.682 us; speedup vs baseline: 3.4838x; 3.4838x over previous
//
#include <hip/hip_runtime.h>
#include <hip/hip_bf16.h>

#define NN 100000
#define FIN 1024
#define NH 8
#define ND 16
#define NC 128
#define NE 600000
#define NP 3
#define NOUT 3

typedef __attribute__((ext_vector_type(8))) short bf16x8;
typedef __attribute__((ext_vector_type(4))) float f32x4;

__device__ __forceinline__ unsigned short f2bf(float f){
  union { __hip_bfloat16 b; unsigned short u; } cv;
  cv.b = __float2bfloat16(f);
  return cv.u;
}
__device__ __forceinline__ float bf2f(__hip_bfloat16 b){ return __bfloat162float(b); }
__device__ __forceinline__ float tanh_fast(float x){
  float e = __expf(2.0f*x);
  return 1.0f - 2.0f/(e + 1.0f);
}
__device__ __forceinline__ float lrelu(float x){ return x > 0.0f ? x : 0.2f*x; }

// ---------------------------------------------------------------- W transpose + bf16 cast
__global__ __launch_bounds__(256) void k_transpose_w(const float* __restrict__ W,
                                                     __hip_bfloat16* __restrict__ Wt){
  int t = blockIdx.x*256 + threadIdx.x;
  if (t >= FIN*NC) return;
  int k = t >> 7, c = t & 127;
  Wt[(size_t)c*FIN + k] = __float2bfloat16(W[t]);
}

// ---------------------------------------------------------------- h = x @ W + b   (bf16 MFMA)
__global__ __launch_bounds__(256) void k_proj(const float* __restrict__ x,
                                              const __hip_bfloat16* __restrict__ Wt,
                                              const float* __restrict__ bias,
                                              __hip_bfloat16* __restrict__ h){
  __shared__ __align__(16) __hip_bfloat16 As[64*40];   // pad 40: 2-way LDS conflicts only (free)
  __shared__ __align__(16) __hip_bfloat16 Bs[128*40];
  const int tid = threadIdx.x;
  const int wave = tid >> 6, lane = tid & 63;
  const int lr = lane & 15, lq = lane >> 4;
  const int m0 = blockIdx.x * 64;
  f32x4 acc[8] = {};
  for (int k0 = 0; k0 < FIN; k0 += 32){
#pragma unroll
    for (int i=0;i<2;i++){
      int idx = tid + 256*i;           // 0..511
      int row = idx >> 3, f4 = idx & 7;
      int gm = m0 + row; if (gm >= NN) gm = NN-1;
      const float4 v = *reinterpret_cast<const float4*>(x + (size_t)gm*FIN + k0 + f4*4);
      ushort4 pk; pk.x=f2bf(v.x); pk.y=f2bf(v.y); pk.z=f2bf(v.z); pk.w=f2bf(v.w);
      *reinterpret_cast<ushort4*>(&As[row*40 + f4*4]) = pk;
    }
#pragma unroll
    for (int i=0;i<2;i++){
      int idx = tid + 256*i;           // 0..511
      int c = idx >> 2, q = idx & 3;
      const uint4 v = *reinterpret_cast<const uint4*>(Wt + (size_t)c*FIN + k0 + q*8);
      *reinterpret_cast<uint4*>(&Bs[c*40 + q*8]) = v;
    }
    __syncthreads();
    bf16x8 afr = *reinterpret_cast<const bf16x8*>(&As[(wave*16 + lr)*40 + lq*8]);
#pragma unroll
    for (int t=0;t<8;t++){
      bf16x8 bfr = *reinterpret_cast<const bf16x8*>(&Bs[(t*16 + lr)*40 + lq*8]);
      acc[t] = __builtin_amdgcn_mfma_f32_16x16x32_bf16(afr, bfr, acc[t], 0, 0, 0);
    }
    __syncthreads();
  }
  // epilogue: D lane map col=lane&15, row=(lane>>4)*4+r
#pragma unroll
  for (int t=0;t<8;t++){
    int col = t*16 + lr;
    float bv = bias[col];
#pragma unroll
    for (int r=0;r<4;r++){
      int gm = m0 + wave*16 + lq*4 + r;
      if (gm < NN) h[(size_t)gm*NC + col] = __float2bfloat16(acc[t][r] + bv);
    }
  }
}

// ---------------------------------------------------------------- per-(node,head) attention logits
__global__ __launch_bounds__(256) void k_al(const __hip_bfloat16* __restrict__ h,
      const float* __restrict__ a_src, const float* __restrict__ a_dst,
      float* __restrict__ al_s, float* __restrict__ al_d){
  int t = blockIdx.x*256 + threadIdx.x;
  if (t >= NN*NH) return;
  int n = t >> 3, hh = t & 7;
  const __hip_bfloat16* hp = h + (size_t)n*NC + hh*ND;
  float hv[ND];
#pragma unroll
  for (int d=0; d<ND; d++) hv[d] = bf2f(hp[d]);
#pragma unroll
  for (int p=0;p<NP;p++){
    const float* as = a_src + (p*NH + hh)*ND;
    const float* ad = a_dst + (p*NH + hh)*ND;
    float ss=0.f, sd=0.f;
#pragma unroll
    for (int d=0;d<ND;d++){ ss += hv[d]*as[d]; sd += hv[d]*ad[d]; }
    al_s[((size_t)p*NN + n)*NH + hh] = ss;
    al_d[((size_t)p*NN + n)*NH + hh] = sd;
  }
}

// ---------------------------------------------------------------- softmax denominator (no max-sub needed: |e|<=~11)
__global__ __launch_bounds__(256) void k_denom(const int* __restrict__ edge,
      const float* __restrict__ al_s, const float* __restrict__ al_d,
      float* __restrict__ denom){
  int p = blockIdx.y;
  int idx = blockIdx.x*256 + threadIdx.x;
  int e = idx >> 3, hh = idx & 7;
  if (e >= NE) return;
  int src = edge[(size_t)p*2*NE + e];
  int dst = edge[(size_t)p*2*NE + NE + e];
  float ev = al_s[((size_t)p*NN + src)*NH + hh] + al_d[((size_t)p*NN + dst)*NH + hh];
  atomicAdd(&denom[((size_t)p*NN + dst)*NH + hh], __expf(lrelu(ev)));
}

// ---------------------------------------------------------------- weighted message scatter
__global__ __launch_bounds__(256) void k_scatter(const int* __restrict__ edge,
      const float* __restrict__ al_s, const float* __restrict__ al_d,
      const float* __restrict__ denom, const __hip_bfloat16* __restrict__ h,
      float* __restrict__ outs){
  int p = blockIdx.y;
  int idx = blockIdx.x*256 + threadIdx.x;
  int e = idx >> 7, c = idx & 127;
  int hh = c >> 4;
  int src = edge[(size_t)p*2*NE + e];
  int dst = edge[(size_t)p*2*NE + NE + e];
  size_t di = ((size_t)p*NN + dst)*NH + hh;
  float ev = al_s[((size_t)p*NN + src)*NH + hh] + al_d[di];
  float alpha = __expf(lrelu(ev)) / (denom[di] + 1e-16f);
  float hv = bf2f(h[(size_t)src*NC + c]);
  atomicAdd(&outs[((size_t)p*NN + dst)*NC + c], alpha*hv);
}

// ---------------------------------------------------------------- semantic att: wsum[p,c] = sum_n tanh(relu(outs)@kW + kb)
// Grid-stride over m-tiles; register accumulation + LDS block-reduce; 128
// global atomics per block (was 2048 per tile → 9.6M same-line atomics = 3.8ms).
__global__ __launch_bounds__(256) void k_semantic(const float* __restrict__ outs,
      const float* __restrict__ kW, const float* __restrict__ kb,
      float* __restrict__ wsum){
  __shared__ __align__(16) __hip_bfloat16 As[64*40];
  __shared__ __align__(16) __hip_bfloat16 Bs[128*136];  // whole kW^T, bf16, pad 136
  __shared__ float wsum_s[NC];
  const int tid = threadIdx.x;
  const int wave = tid >> 6, lane = tid & 63;
  const int lr = lane & 15, lq = lane >> 4;
  const int p = blockIdx.y;
  const float* op = outs + (size_t)p*NN*NC;
  // stage kW^T once per block
  for (int i=tid; i<NC*NC; i+=256){
    int k = i >> 7, c = i & 127;
    Bs[c*136 + k] = __float2bfloat16(kW[i]);
  }
  if (tid < NC) wsum_s[tid] = 0.f;
  float kbv[8];
#pragma unroll
  for (int t=0;t<8;t++) kbv[t] = kb[t*16 + lr];
  float ps[8] = {};
  const int ntiles = (NN + 63)/64;
  for (int tile = blockIdx.x; tile < ntiles; tile += gridDim.x){
    const int m0 = tile*64;
    f32x4 acc[8] = {};
    for (int k0=0; k0<NC; k0+=32){
#pragma unroll
      for (int i=0;i<2;i++){
        int idx = tid + 256*i;
        int row = idx >> 3, f4 = idx & 7;
        int gm = m0 + row; if (gm >= NN) gm = NN-1;
        float4 v = *reinterpret_cast<const float4*>(op + (size_t)gm*NC + k0 + f4*4);
        ushort4 pk;
        pk.x=f2bf(fmaxf(v.x,0.f)); pk.y=f2bf(fmaxf(v.y,0.f));
        pk.z=f2bf(fmaxf(v.z,0.f)); pk.w=f2bf(fmaxf(v.w,0.f));
        *reinterpret_cast<ushort4*>(&As[row*40 + f4*4]) = pk;
      }
      __syncthreads();   // also covers one-time Bs/wsum_s staging on first iter
      bf16x8 afr = *reinterpret_cast<const bf16x8*>(&As[(wave*16 + lr)*40 + lq*8]);
#pragma unroll
      for (int t=0;t<8;t++){
        bf16x8 bfr = *reinterpret_cast<const bf16x8*>(&Bs[(t*16 + lr)*136 + k0 + lq*8]);
        acc[t] = __builtin_amdgcn_mfma_f32_16x16x32_bf16(afr, bfr, acc[t], 0, 0, 0);
      }
      __syncthreads();
    }
#pragma unroll
    for (int t=0;t<8;t++){
#pragma unroll
      for (int r=0;r<4;r++){
        int gm = m0 + wave*16 + lq*4 + r;
        if (gm < NN) ps[t] += tanh_fast(acc[t][r] + kbv[t]);
      }
    }
  }
  // block-level reduce: LDS atomics (16 writers/column), then 128 global atomics
#pragma unroll
  for (int t=0;t<8;t++) atomicAdd(&wsum_s[t*16 + lr], ps[t]);
  __syncthreads();
  if (tid < NC) atomicAdd(&wsum[p*NC + tid], wsum_s[tid]);
}

// ---------------------------------------------------------------- beta = softmax(q . mean_tanh)
__global__ void k_beta(const float* __restrict__ wsum, const float* __restrict__ qv,
                       float* __restrict__ beta){
  int lane = threadIdx.x;  // 64 threads
  float s[NP];
#pragma unroll
  for (int p=0;p<NP;p++){
    float acc = wsum[p*NC + lane]*qv[lane] + wsum[p*NC + lane + 64]*qv[lane + 64];
#pragma unroll
    for (int off=32; off>0; off>>=1) acc += __shfl_down(acc, off);
    s[p] = acc;
  }
  if (lane == 0){
    float sc0 = s[0]/(float)NN, sc1 = s[1]/(float)NN, sc2 = s[2]/(float)NN;
    float mx = fmaxf(sc0, fmaxf(sc1, sc2));
    float e0 = __expf(sc0-mx), e1 = __expf(sc1-mx), e2 = __expf(sc2-mx);
    float inv = 1.0f/(e0+e1+e2);
    beta[0]=e0*inv; beta[1]=e1*inv; beta[2]=e2*inv;
  }
}

// ---------------------------------------------------------------- fused = sum_p beta_p relu(outs_p); out = fused@linW + linb
__global__ __launch_bounds__(256) void k_fuse(const float* __restrict__ outs,
      const float* __restrict__ beta, const float* __restrict__ linW,
      const float* __restrict__ linb, float* __restrict__ out){
  int node = blockIdx.x*4 + (threadIdx.x >> 6);
  int lane = threadIdx.x & 63;
  if (node >= NN) return;
  float b0 = beta[0], b1 = beta[1], b2 = beta[2];
  float a0=0.f, a1=0.f, a2=0.f;
#pragma unroll
  for (int i=0;i<2;i++){
    int c = lane + i*64;
    float f = b0*fmaxf(outs[((size_t)0*NN + node)*NC + c], 0.f)
            + b1*fmaxf(outs[((size_t)1*NN + node)*NC + c], 0.f)
            + b2*fmaxf(outs[((size_t)2*NN + node)*NC + c], 0.f);
    a0 += f*linW[c*NOUT + 0];
    a1 += f*linW[c*NOUT + 1];
    a2 += f*linW[c*NOUT + 2];
  }
#pragma unroll
  for (int off=32; off>0; off>>=1){
    a0 += __shfl_down(a0, off);
    a1 += __shfl_down(a1, off);
    a2 += __shfl_down(a2, off);
  }
  if (lane == 0){
    out[(size_t)node*NOUT + 0] = a0 + linb[0];
    out[(size_t)node*NOUT + 1] = a1 + linb[1];
    out[(size_t)node*NOUT + 2] = a2 + linb[2];
  }
}

extern "C" void kernel_launch(void* const* d_in, const int* in_sizes, int n_in,
                              void* d_out, int out_size, void* d_ws, size_t ws_size,
                              hipStream_t stream){
  const float* x     = (const float*)d_in[0];
  const int*   edge  = (const int*)d_in[1];
  const float* Wp    = (const float*)d_in[2];
  const float* bp    = (const float*)d_in[3];
  const float* a_src = (const float*)d_in[4];
  const float* a_dst = (const float*)d_in[5];
  const float* kW    = (const float*)d_in[6];
  const float* kb    = (const float*)d_in[7];
  const float* qv    = (const float*)d_in[8];
  const float* linW  = (const float*)d_in[9];
  const float* linb  = (const float*)d_in[10];
  float* out = (float*)d_out;
  char* ws = (char*)d_ws;

  __hip_bfloat16* Wt   = (__hip_bfloat16*)(ws + 0);          //   262,144
  __hip_bfloat16* h    = (__hip_bfloat16*)(ws + 262144);     //  25,600,000
  float* al_s  = (float*)(ws + 25862144);                    //   9,600,000
  float* al_d  = (float*)(ws + 35462144);                    //   9,600,000
  float* denom = (float*)(ws + 45062144);                    //   9,600,000
  float* outs  = (float*)(ws + 54662144);                    // 153,600,000
  float* wsum  = (float*)(ws + 208262144);                   //       1,536
  float* beta  = (float*)(ws + 208263680);                   //          12

  hipMemsetAsync(denom, 0, (size_t)NP*NN*NH*4, stream);
  hipMemsetAsync(outs,  0, (size_t)NP*NN*NC*4, stream);
  hipMemsetAsync(wsum,  0, NP*NC*4, stream);

  k_transpose_w<<<(FIN*NC + 255)/256, 256, 0, stream>>>(Wp, Wt);
  k_proj<<<(NN + 63)/64, 256, 0, stream>>>(x, Wt, bp, h);
  k_al<<<(NN*NH + 255)/256, 256, 0, stream>>>(h, a_src, a_dst, al_s, al_d);
  k_denom<<<dim3(NE*NH/256, NP), 256, 0, stream>>>(edge, al_s, al_d, denom);
  k_scatter<<<dim3(NE*NC/256, NP), 256, 0, stream>>>(edge, al_s, al_d, denom, h, outs);
  k_semantic<<<dim3(256, NP), 256, 0, stream>>>(outs, kW, kb, wsum);
  k_beta<<<1, 64, 0, stream>>>(wsum, qv, beta);
  k_fuse<<<(NN + 3)/4, 256, 0, stream>>>(outs, beta, linW, linb, out);
}

// Round 3
// 1290.701 us; speedup vs baseline: 4.4446x; 1.2758x over previous
//
#include <hip/hip_runtime.h>
#include <hip/hip_bf16.h>

#define NN 100000
#define FIN 1024
#define NH 8
#define ND 16
#define NC 128
#define NE 600000
#define NP 3
#define NOUT 3
#define NBLK 98   // ceil(NN/1024) for the scan

typedef __attribute__((ext_vector_type(8))) short bf16x8;
typedef __attribute__((ext_vector_type(4))) float f32x4;

__device__ __forceinline__ unsigned short f2bf(float f){
  union { __hip_bfloat16 b; unsigned short u; } cv;
  cv.b = __float2bfloat16(f);
  return cv.u;
}
__device__ __forceinline__ float bf2f(__hip_bfloat16 b){ return __bfloat162float(b); }
__device__ __forceinline__ float tanh_fast(float x){
  float e = __expf(2.0f*x);
  return 1.0f - 2.0f/(e + 1.0f);
}
__device__ __forceinline__ float lrelu(float x){ return x > 0.0f ? x : 0.2f*x; }

// ---------------------------------------------------------------- W transpose + bf16 cast
__global__ __launch_bounds__(256) void k_transpose_w(const float* __restrict__ W,
                                                     __hip_bfloat16* __restrict__ Wt){
  int t = blockIdx.x*256 + threadIdx.x;
  if (t >= FIN*NC) return;
  int k = t >> 7, c = t & 127;
  Wt[(size_t)c*FIN + k] = __float2bfloat16(W[t]);
}

// ---------------------------------------------------------------- h = x @ W + b   (bf16 MFMA)
__global__ __launch_bounds__(256) void k_proj(const float* __restrict__ x,
                                              const __hip_bfloat16* __restrict__ Wt,
                                              const float* __restrict__ bias,
                                              __hip_bfloat16* __restrict__ h){
  __shared__ __align__(16) __hip_bfloat16 As[64*40];   // pad 40: 2-way LDS conflicts only (free)
  __shared__ __align__(16) __hip_bfloat16 Bs[128*40];
  const int tid = threadIdx.x;
  const int wave = tid >> 6, lane = tid & 63;
  const int lr = lane & 15, lq = lane >> 4;
  const int m0 = blockIdx.x * 64;
  f32x4 acc[8] = {};
  for (int k0 = 0; k0 < FIN; k0 += 32){
#pragma unroll
    for (int i=0;i<2;i++){
      int idx = tid + 256*i;           // 0..511
      int row = idx >> 3, f4 = idx & 7;
      int gm = m0 + row; if (gm >= NN) gm = NN-1;
      const float4 v = *reinterpret_cast<const float4*>(x + (size_t)gm*FIN + k0 + f4*4);
      ushort4 pk; pk.x=f2bf(v.x); pk.y=f2bf(v.y); pk.z=f2bf(v.z); pk.w=f2bf(v.w);
      *reinterpret_cast<ushort4*>(&As[row*40 + f4*4]) = pk;
    }
#pragma unroll
    for (int i=0;i<2;i++){
      int idx = tid + 256*i;           // 0..511
      int c = idx >> 2, q = idx & 3;
      const uint4 v = *reinterpret_cast<const uint4*>(Wt + (size_t)c*FIN + k0 + q*8);
      *reinterpret_cast<uint4*>(&Bs[c*40 + q*8]) = v;
    }
    __syncthreads();
    bf16x8 afr = *reinterpret_cast<const bf16x8*>(&As[(wave*16 + lr)*40 + lq*8]);
#pragma unroll
    for (int t=0;t<8;t++){
      bf16x8 bfr = *reinterpret_cast<const bf16x8*>(&Bs[(t*16 + lr)*40 + lq*8]);
      acc[t] = __builtin_amdgcn_mfma_f32_16x16x32_bf16(afr, bfr, acc[t], 0, 0, 0);
    }
    __syncthreads();
  }
  // epilogue: D lane map col=lane&15, row=(lane>>4)*4+r
#pragma unroll
  for (int t=0;t<8;t++){
    int col = t*16 + lr;
    float bv = bias[col];
#pragma unroll
    for (int r=0;r<4;r++){
      int gm = m0 + wave*16 + lq*4 + r;
      if (gm < NN) h[(size_t)gm*NC + col] = __float2bfloat16(acc[t][r] + bv);
    }
  }
}

// ---------------------------------------------------------------- per-(node,head) attention logits
__global__ __launch_bounds__(256) void k_al(const __hip_bfloat16* __restrict__ h,
      const float* __restrict__ a_src, const float* __restrict__ a_dst,
      float* __restrict__ al_s, float* __restrict__ al_d){
  int t = blockIdx.x*256 + threadIdx.x;
  if (t >= NN*NH) return;
  int n = t >> 3, hh = t & 7;
  const __hip_bfloat16* hp = h + (size_t)n*NC + hh*ND;
  float hv[ND];
#pragma unroll
  for (int d=0; d<ND; d++) hv[d] = bf2f(hp[d]);
#pragma unroll
  for (int p=0;p<NP;p++){
    const float* as = a_src + (p*NH + hh)*ND;
    const float* ad = a_dst + (p*NH + hh)*ND;
    float ss=0.f, sd=0.f;
#pragma unroll
    for (int d=0;d<ND;d++){ ss += hv[d]*as[d]; sd += hv[d]*ad[d]; }
    al_s[((size_t)p*NN + n)*NH + hh] = ss;
    al_d[((size_t)p*NN + n)*NH + hh] = sd;
  }
}

// ---------------------------------------------------------------- CSR build: degree histogram
__global__ __launch_bounds__(256) void k_deg(const int* __restrict__ edge,
                                             int* __restrict__ deg){
  int p = blockIdx.y;
  int e = blockIdx.x*256 + threadIdx.x;
  if (e >= NE) return;
  int dst = edge[(size_t)p*2*NE + NE + e];
  atomicAdd(&deg[p*NN + dst], 1);
}

// exclusive scan, stage 1: per-1024-chunk scan + chunk totals
__global__ __launch_bounds__(256) void k_scan_blk(const int* __restrict__ deg,
      int* __restrict__ row_start, int* __restrict__ blksum){
  __shared__ int sums[256];
  int p = blockIdx.y, blk = blockIdx.x, tid = threadIdx.x;
  int base = blk*1024 + tid*4;
  int v[4];
#pragma unroll
  for (int i=0;i<4;i++){
    int idx = base+i;
    v[i] = (idx < NN) ? deg[p*NN+idx] : 0;
  }
  int s = v[0]+v[1]+v[2]+v[3];
  sums[tid] = s;
  __syncthreads();
  for (int off=1; off<256; off<<=1){
    int t = (tid >= off) ? sums[tid-off] : 0;
    __syncthreads();
    sums[tid] += t;
    __syncthreads();
  }
  int run = sums[tid] - s;   // exclusive prefix within chunk
  if (tid == 255) blksum[p*128 + blk] = sums[255];
  #pragma unroll
  for (int i=0;i<4;i++){
    int idx = base+i;
    if (idx < NN) row_start[p*(NN+1)+idx] = run;
    run += v[i];
  }
}

// stage 2: scan the 98 chunk totals (one block per p)
__global__ void k_scan_top(int* __restrict__ blksum){
  __shared__ int s[128];
  int p = blockIdx.x, tid = threadIdx.x;  // 128 threads
  int v = (tid < NBLK) ? blksum[p*128+tid] : 0;
  s[tid] = v;
  __syncthreads();
  for (int off=1; off<128; off<<=1){
    int t = (tid>=off) ? s[tid-off] : 0;
    __syncthreads();
    s[tid] += t;
    __syncthreads();
  }
  blksum[p*128+tid] = s[tid] - v;  // exclusive
}

// stage 3: add chunk offsets; init cursor; write sentinel
__global__ __launch_bounds__(256) void k_scan_add(int* __restrict__ row_start,
      const int* __restrict__ blksum, int* __restrict__ cursor){
  int p = blockIdx.y, blk = blockIdx.x, tid = threadIdx.x;
  int add = blksum[p*128+blk];
  int base = blk*1024 + tid*4;
#pragma unroll
  for (int i=0;i<4;i++){
    int idx = base+i;
    if (idx < NN){
      int vv = row_start[p*(NN+1)+idx] + add;
      row_start[p*(NN+1)+idx] = vv;
      cursor[p*NN+idx] = vv;
    }
  }
  if (blk==0 && tid==0) row_start[p*(NN+1)+NN] = NE;
}

// fill: csr_src[p][pos] = src for edges grouped by dst
__global__ __launch_bounds__(256) void k_fill(const int* __restrict__ edge,
      int* __restrict__ cursor, int* __restrict__ csr_src){
  int p = blockIdx.y;
  int e = blockIdx.x*256 + threadIdx.x;
  if (e >= NE) return;
  int src = edge[(size_t)p*2*NE + e];
  int dst = edge[(size_t)p*2*NE + NE + e];
  int pos = atomicAdd(&cursor[p*NN + dst], 1);
  csr_src[(size_t)p*NE + pos] = src;
}

// ---------------------------------------------------------------- gather: wave per (p,dst), 2 ch/lane
// pass 1 over row: softmax denom (replaces k_denom); pass 2: weighted sum.
// Single coalesced float2 store per (dst,channel-pair) — no atomics, no outs memset.
__global__ __launch_bounds__(256) void k_gather(const int* __restrict__ row_start,
      const int* __restrict__ csr_src, const __hip_bfloat16* __restrict__ h,
      const float* __restrict__ al_s, const float* __restrict__ al_d,
      float* __restrict__ outs){
  int p = blockIdx.y;
  int dst = blockIdx.x*4 + (threadIdx.x >> 6);
  int lane = threadIdx.x & 63;
  if (dst >= NN) return;
  int hh = lane >> 3;                       // head of channels {2*lane, 2*lane+1}
  int beg = row_start[p*(NN+1)+dst], end = row_start[p*(NN+1)+dst+1];
  float ald = al_d[((size_t)p*NN + dst)*NH + hh];
  const int*   cs  = csr_src + (size_t)p*NE;
  const float* als = al_s + (size_t)p*NN*NH;
  float denom = 0.f;
  for (int e=beg; e<end; e++){
    int src = cs[e];
    denom += __expf(lrelu(als[src*NH + hh] + ald));
  }
  float inv = 1.f/(denom + 1e-16f);
  float a0=0.f, a1=0.f;
  for (int e=beg; e<end; e++){
    int src = cs[e];
    float w = __expf(lrelu(als[src*NH + hh] + ald)) * inv;
    unsigned int hv = *reinterpret_cast<const unsigned int*>(h + (size_t)src*NC + lane*2);
    __hip_bfloat162 h2 = *reinterpret_cast<__hip_bfloat162*>(&hv);
    a0 += w * bf2f(h2.x);
    a1 += w * bf2f(h2.y);
  }
  float2 o; o.x = fmaxf(a0, 0.f); o.y = fmaxf(a1, 0.f);   // relu fused here
  *reinterpret_cast<float2*>(outs + ((size_t)p*NN + dst)*NC + lane*2) = o;
}

// ---------------------------------------------------------------- semantic att: wsum[p,c] = sum_n tanh(outs@kW + kb)
__global__ __launch_bounds__(256) void k_semantic(const float* __restrict__ outs,
      const float* __restrict__ kW, const float* __restrict__ kb,
      float* __restrict__ wsum){
  __shared__ __align__(16) __hip_bfloat16 As[64*40];
  __shared__ __align__(16) __hip_bfloat16 Bs[128*136];  // whole kW^T, bf16, pad 136
  __shared__ float wsum_s[NC];
  const int tid = threadIdx.x;
  const int wave = tid >> 6, lane = tid & 63;
  const int lr = lane & 15, lq = lane >> 4;
  const int p = blockIdx.y;
  const float* op = outs + (size_t)p*NN*NC;
  for (int i=tid; i<NC*NC; i+=256){
    int k = i >> 7, c = i & 127;
    Bs[c*136 + k] = __float2bfloat16(kW[i]);
  }
  if (tid < NC) wsum_s[tid] = 0.f;
  float kbv[8];
#pragma unroll
  for (int t=0;t<8;t++) kbv[t] = kb[t*16 + lr];
  float ps[8] = {};
  const int ntiles = (NN + 63)/64;
  for (int tile = blockIdx.x; tile < ntiles; tile += gridDim.x){
    const int m0 = tile*64;
    f32x4 acc[8] = {};
    for (int k0=0; k0<NC; k0+=32){
#pragma unroll
      for (int i=0;i<2;i++){
        int idx = tid + 256*i;
        int row = idx >> 3, f4 = idx & 7;
        int gm = m0 + row; if (gm >= NN) gm = NN-1;
        float4 v = *reinterpret_cast<const float4*>(op + (size_t)gm*NC + k0 + f4*4);
        ushort4 pk;
        pk.x=f2bf(v.x); pk.y=f2bf(v.y); pk.z=f2bf(v.z); pk.w=f2bf(v.w);  // outs already relu'd
        *reinterpret_cast<ushort4*>(&As[row*40 + f4*4]) = pk;
      }
      __syncthreads();
      bf16x8 afr = *reinterpret_cast<const bf16x8*>(&As[(wave*16 + lr)*40 + lq*8]);
#pragma unroll
      for (int t=0;t<8;t++){
        bf16x8 bfr = *reinterpret_cast<const bf16x8*>(&Bs[(t*16 + lr)*136 + k0 + lq*8]);
        acc[t] = __builtin_amdgcn_mfma_f32_16x16x32_bf16(afr, bfr, acc[t], 0, 0, 0);
      }
      __syncthreads();
    }
#pragma unroll
    for (int t=0;t<8;t++){
#pragma unroll
      for (int r=0;r<4;r++){
        int gm = m0 + wave*16 + lq*4 + r;
        if (gm < NN) ps[t] += tanh_fast(acc[t][r] + kbv[t]);
      }
    }
  }
#pragma unroll
  for (int t=0;t<8;t++) atomicAdd(&wsum_s[t*16 + lr], ps[t]);
  __syncthreads();
  if (tid < NC) atomicAdd(&wsum[p*NC + tid], wsum_s[tid]);
}

// ---------------------------------------------------------------- beta = softmax(q . mean_tanh)
__global__ void k_beta(const float* __restrict__ wsum, const float* __restrict__ qv,
                       float* __restrict__ beta){
  int lane = threadIdx.x;  // 64 threads
  float s[NP];
#pragma unroll
  for (int p=0;p<NP;p++){
    float acc = wsum[p*NC + lane]*qv[lane] + wsum[p*NC + lane + 64]*qv[lane + 64];
#pragma unroll
    for (int off=32; off>0; off>>=1) acc += __shfl_down(acc, off);
    s[p] = acc;
  }
  if (lane == 0){
    float sc0 = s[0]/(float)NN, sc1 = s[1]/(float)NN, sc2 = s[2]/(float)NN;
    float mx = fmaxf(sc0, fmaxf(sc1, sc2));
    float e0 = __expf(sc0-mx), e1 = __expf(sc1-mx), e2 = __expf(sc2-mx);
    float inv = 1.0f/(e0+e1+e2);
    beta[0]=e0*inv; beta[1]=e1*inv; beta[2]=e2*inv;
  }
}

// ---------------------------------------------------------------- fused = sum_p beta_p outs_p; out = fused@linW + linb
__global__ __launch_bounds__(256) void k_fuse(const float* __restrict__ outs,
      const float* __restrict__ beta, const float* __restrict__ linW,
      const float* __restrict__ linb, float* __restrict__ out){
  int node = blockIdx.x*4 + (threadIdx.x >> 6);
  int lane = threadIdx.x & 63;
  if (node >= NN) return;
  float b0 = beta[0], b1 = beta[1], b2 = beta[2];
  float a0=0.f, a1=0.f, a2=0.f;
#pragma unroll
  for (int i=0;i<2;i++){
    int c = lane + i*64;
    float f = b0*outs[((size_t)0*NN + node)*NC + c]
            + b1*outs[((size_t)1*NN + node)*NC + c]
            + b2*outs[((size_t)2*NN + node)*NC + c];   // outs already relu'd
    a0 += f*linW[c*NOUT + 0];
    a1 += f*linW[c*NOUT + 1];
    a2 += f*linW[c*NOUT + 2];
  }
#pragma unroll
  for (int off=32; off>0; off>>=1){
    a0 += __shfl_down(a0, off);
    a1 += __shfl_down(a1, off);
    a2 += __shfl_down(a2, off);
  }
  if (lane == 0){
    out[(size_t)node*NOUT + 0] = a0 + linb[0];
    out[(size_t)node*NOUT + 1] = a1 + linb[1];
    out[(size_t)node*NOUT + 2] = a2 + linb[2];
  }
}

extern "C" void kernel_launch(void* const* d_in, const int* in_sizes, int n_in,
                              void* d_out, int out_size, void* d_ws, size_t ws_size,
                              hipStream_t stream){
  const float* x     = (const float*)d_in[0];
  const int*   edge  = (const int*)d_in[1];
  const float* Wp    = (const float*)d_in[2];
  const float* bp    = (const float*)d_in[3];
  const float* a_src = (const float*)d_in[4];
  const float* a_dst = (const float*)d_in[5];
  const float* kW    = (const float*)d_in[6];
  const float* kb    = (const float*)d_in[7];
  const float* qv    = (const float*)d_in[8];
  const float* linW  = (const float*)d_in[9];
  const float* linb  = (const float*)d_in[10];
  float* out = (float*)d_out;
  char* ws = (char*)d_ws;

  // workspace layout (bytes), total ~208.27 MB (same footprint as r2)
  __hip_bfloat16* Wt  = (__hip_bfloat16*)(ws + 0);           //    262,144
  __hip_bfloat16* h   = (__hip_bfloat16*)(ws + 262144);      // 25,600,000
  float* al_s   = (float*)(ws + 25862144);                   //  9,600,000
  float* al_d   = (float*)(ws + 35462144);                   //  9,600,000
  int* deg      = (int*)(ws + 45062144);                     //  1,200,000 (reused as cursor)
  int* row_start= (int*)(ws + 46262144);                     //  1,200,016
  int* blksum   = (int*)(ws + 47462160);                     //      1,536
  int* csr_src  = (int*)(ws + 47463696);                     //  7,200,000
  float* outs   = (float*)(ws + 54663696);                   //153,600,000
  float* wsum   = (float*)(ws + 208263696);                  //      1,536
  float* beta   = (float*)(ws + 208265232);                  //         12
  int* cursor   = deg;                                       // alias: deg dead after scan

  hipMemsetAsync(deg,  0, (size_t)NP*NN*4, stream);
  hipMemsetAsync(wsum, 0, NP*NC*4, stream);

  k_transpose_w<<<(FIN*NC + 255)/256, 256, 0, stream>>>(Wp, Wt);
  k_proj<<<(NN + 63)/64, 256, 0, stream>>>(x, Wt, bp, h);
  k_al<<<(NN*NH + 255)/256, 256, 0, stream>>>(h, a_src, a_dst, al_s, al_d);
  k_deg<<<dim3((NE + 255)/256, NP), 256, 0, stream>>>(edge, deg);
  k_scan_blk<<<dim3(NBLK, NP), 256, 0, stream>>>(deg, row_start, blksum);
  k_scan_top<<<NP, 128, 0, stream>>>(blksum);
  k_scan_add<<<dim3(NBLK, NP), 256, 0, stream>>>(row_start, blksum, cursor);
  k_fill<<<dim3((NE + 255)/256, NP), 256, 0, stream>>>(edge, cursor, csr_src);
  k_gather<<<dim3((NN + 3)/4, NP), 256, 0, stream>>>(row_start, csr_src, h, al_s, al_d, outs);
  k_semantic<<<dim3(256, NP), 256, 0, stream>>>(outs, kW, kb, wsum);
  k_beta<<<1, 64, 0, stream>>>(wsum, qv, beta);
  k_fuse<<<(NN + 3)/4, 256, 0, stream>>>(outs, beta, linW, linb, out);
}

// Round 4
// 1080.651 us; speedup vs baseline: 5.3085x; 1.1944x over previous
//
#include <hip/hip_runtime.h>
#include <hip/hip_bf16.h>

#define NN 100000
#define FIN 1024
#define NH 8
#define ND 16
#define NC 128
#define NE 600000
#define NP 3
#define NOUT 3
#define NBLK 98   // ceil(NN/1024) for the scan

typedef __attribute__((ext_vector_type(8))) short bf16x8;
typedef __attribute__((ext_vector_type(4))) float f32x4;

__device__ __forceinline__ unsigned short f2bf(float f){
  union { __hip_bfloat16 b; unsigned short u; } cv;
  cv.b = __float2bfloat16(f);
  return cv.u;
}
__device__ __forceinline__ float bf2f(__hip_bfloat16 b){ return __bfloat162float(b); }
__device__ __forceinline__ float tanh_fast(float x){
  float e = __expf(2.0f*x);
  return 1.0f - 2.0f/(e + 1.0f);
}
__device__ __forceinline__ float lrelu(float x){ return x > 0.0f ? x : 0.2f*x; }

// ---------------------------------------------------------------- W transpose + bf16 cast
__global__ __launch_bounds__(256) void k_transpose_w(const float* __restrict__ W,
                                                     __hip_bfloat16* __restrict__ Wt){
  int t = blockIdx.x*256 + threadIdx.x;
  if (t >= FIN*NC) return;
  int k = t >> 7, c = t & 127;
  Wt[(size_t)c*FIN + k] = __float2bfloat16(W[t]);
}

// ---------------------------------------------------------------- h = x @ W + b   (bf16 MFMA)
__global__ __launch_bounds__(256) void k_proj(const float* __restrict__ x,
                                              const __hip_bfloat16* __restrict__ Wt,
                                              const float* __restrict__ bias,
                                              __hip_bfloat16* __restrict__ h){
  __shared__ __align__(16) __hip_bfloat16 As[64*40];   // pad 40: 2-way LDS conflicts only (free)
  __shared__ __align__(16) __hip_bfloat16 Bs[128*40];
  const int tid = threadIdx.x;
  const int wave = tid >> 6, lane = tid & 63;
  const int lr = lane & 15, lq = lane >> 4;
  const int m0 = blockIdx.x * 64;
  f32x4 acc[8] = {};
  for (int k0 = 0; k0 < FIN; k0 += 32){
#pragma unroll
    for (int i=0;i<2;i++){
      int idx = tid + 256*i;           // 0..511
      int row = idx >> 3, f4 = idx & 7;
      int gm = m0 + row; if (gm >= NN) gm = NN-1;
      const float4 v = *reinterpret_cast<const float4*>(x + (size_t)gm*FIN + k0 + f4*4);
      ushort4 pk; pk.x=f2bf(v.x); pk.y=f2bf(v.y); pk.z=f2bf(v.z); pk.w=f2bf(v.w);
      *reinterpret_cast<ushort4*>(&As[row*40 + f4*4]) = pk;
    }
#pragma unroll
    for (int i=0;i<2;i++){
      int idx = tid + 256*i;           // 0..511
      int c = idx >> 2, q = idx & 3;
      const uint4 v = *reinterpret_cast<const uint4*>(Wt + (size_t)c*FIN + k0 + q*8);
      *reinterpret_cast<uint4*>(&Bs[c*40 + q*8]) = v;
    }
    __syncthreads();
    bf16x8 afr = *reinterpret_cast<const bf16x8*>(&As[(wave*16 + lr)*40 + lq*8]);
#pragma unroll
    for (int t=0;t<8;t++){
      bf16x8 bfr = *reinterpret_cast<const bf16x8*>(&Bs[(t*16 + lr)*40 + lq*8]);
      acc[t] = __builtin_amdgcn_mfma_f32_16x16x32_bf16(afr, bfr, acc[t], 0, 0, 0);
    }
    __syncthreads();
  }
  // epilogue: D lane map col=lane&15, row=(lane>>4)*4+r
#pragma unroll
  for (int t=0;t<8;t++){
    int col = t*16 + lr;
    float bv = bias[col];
#pragma unroll
    for (int r=0;r<4;r++){
      int gm = m0 + wave*16 + lq*4 + r;
      if (gm < NN) h[(size_t)gm*NC + col] = __float2bfloat16(acc[t][r] + bv);
    }
  }
}

// ---------------------------------------------------------------- per-(node,head) attention logits
__global__ __launch_bounds__(256) void k_al(const __hip_bfloat16* __restrict__ h,
      const float* __restrict__ a_src, const float* __restrict__ a_dst,
      float* __restrict__ al_s, float* __restrict__ al_d){
  int t = blockIdx.x*256 + threadIdx.x;
  if (t >= NN*NH) return;
  int n = t >> 3, hh = t & 7;
  const __hip_bfloat16* hp = h + (size_t)n*NC + hh*ND;
  float hv[ND];
#pragma unroll
  for (int d=0; d<ND; d++) hv[d] = bf2f(hp[d]);
#pragma unroll
  for (int p=0;p<NP;p++){
    const float* as = a_src + (p*NH + hh)*ND;
    const float* ad = a_dst + (p*NH + hh)*ND;
    float ss=0.f, sd=0.f;
#pragma unroll
    for (int d=0;d<ND;d++){ ss += hv[d]*as[d]; sd += hv[d]*ad[d]; }
    al_s[((size_t)p*NN + n)*NH + hh] = ss;
    al_d[((size_t)p*NN + n)*NH + hh] = sd;
  }
}

// ---------------------------------------------------------------- CSR build: degree histogram
__global__ __launch_bounds__(256) void k_deg(const int* __restrict__ edge,
                                             int* __restrict__ deg){
  int p = blockIdx.y;
  int e = blockIdx.x*256 + threadIdx.x;
  if (e >= NE) return;
  int dst = edge[(size_t)p*2*NE + NE + e];
  atomicAdd(&deg[p*NN + dst], 1);
}

// exclusive scan, stage 1: per-1024-chunk scan + chunk totals
__global__ __launch_bounds__(256) void k_scan_blk(const int* __restrict__ deg,
      int* __restrict__ row_start, int* __restrict__ blksum){
  __shared__ int sums[256];
  int p = blockIdx.y, blk = blockIdx.x, tid = threadIdx.x;
  int base = blk*1024 + tid*4;
  int v[4];
#pragma unroll
  for (int i=0;i<4;i++){
    int idx = base+i;
    v[i] = (idx < NN) ? deg[p*NN+idx] : 0;
  }
  int s = v[0]+v[1]+v[2]+v[3];
  sums[tid] = s;
  __syncthreads();
  for (int off=1; off<256; off<<=1){
    int t = (tid >= off) ? sums[tid-off] : 0;
    __syncthreads();
    sums[tid] += t;
    __syncthreads();
  }
  int run = sums[tid] - s;   // exclusive prefix within chunk
  if (tid == 255) blksum[p*128 + blk] = sums[255];
  #pragma unroll
  for (int i=0;i<4;i++){
    int idx = base+i;
    if (idx < NN) row_start[p*(NN+1)+idx] = run;
    run += v[i];
  }
}

// stage 2: scan the 98 chunk totals (one block per p)
__global__ void k_scan_top(int* __restrict__ blksum){
  __shared__ int s[128];
  int p = blockIdx.x, tid = threadIdx.x;  // 128 threads
  int v = (tid < NBLK) ? blksum[p*128+tid] : 0;
  s[tid] = v;
  __syncthreads();
  for (int off=1; off<128; off<<=1){
    int t = (tid>=off) ? s[tid-off] : 0;
    __syncthreads();
    s[tid] += t;
    __syncthreads();
  }
  blksum[p*128+tid] = s[tid] - v;  // exclusive
}

// stage 3: add chunk offsets; init cursor; write sentinel
__global__ __launch_bounds__(256) void k_scan_add(int* __restrict__ row_start,
      const int* __restrict__ blksum, int* __restrict__ cursor){
  int p = blockIdx.y, blk = blockIdx.x, tid = threadIdx.x;
  int add = blksum[p*128+blk];
  int base = blk*1024 + tid*4;
#pragma unroll
  for (int i=0;i<4;i++){
    int idx = base+i;
    if (idx < NN){
      int vv = row_start[p*(NN+1)+idx] + add;
      row_start[p*(NN+1)+idx] = vv;
      cursor[p*NN+idx] = vv;
    }
  }
  if (blk==0 && tid==0) row_start[p*(NN+1)+NN] = NE;
}

// fill: csr_src[p][pos] = src for edges grouped by dst
__global__ __launch_bounds__(256) void k_fill(const int* __restrict__ edge,
      int* __restrict__ cursor, int* __restrict__ csr_src){
  int p = blockIdx.y;
  int e = blockIdx.x*256 + threadIdx.x;
  if (e >= NE) return;
  int src = edge[(size_t)p*2*NE + e];
  int dst = edge[(size_t)p*2*NE + NE + e];
  int pos = atomicAdd(&cursor[p*NN + dst], 1);
  csr_src[(size_t)p*NE + pos] = src;
}

// ---------------------------------------------------------------- gather: wave per (p,dst), 2 ch/lane
// SINGLE PASS: accumulate unnormalized sum + weight total, normalize at end.
// alpha_e = w_e/Σw  ⇒  out = (Σ w_e h_e)/Σw — identical math, half the loop trips.
__global__ __launch_bounds__(256) void k_gather(const int* __restrict__ row_start,
      const int* __restrict__ csr_src, const __hip_bfloat16* __restrict__ h,
      const float* __restrict__ al_s, const float* __restrict__ al_d,
      __hip_bfloat16* __restrict__ outs){
  int p = blockIdx.y;
  int dst = blockIdx.x*4 + (threadIdx.x >> 6);
  int lane = threadIdx.x & 63;
  if (dst >= NN) return;
  int hh = lane >> 3;                       // head of channels {2*lane, 2*lane+1}
  int beg = row_start[p*(NN+1)+dst], end = row_start[p*(NN+1)+dst+1];
  float ald = al_d[((size_t)p*NN + dst)*NH + hh];
  const int*   cs  = csr_src + (size_t)p*NE;
  const float* als = al_s + (size_t)p*NN*NH;
  float wsum = 0.f, a0 = 0.f, a1 = 0.f;
  int src_next = (beg < end) ? cs[beg] : 0;
  for (int e=beg; e<end; e++){
    int src = src_next;
    if (e+1 < end) src_next = cs[e+1];     // prefetch: decouple dependent chain
    float w = __expf(lrelu(als[src*NH + hh] + ald));
    unsigned int hv = *reinterpret_cast<const unsigned int*>(h + (size_t)src*NC + lane*2);
    __hip_bfloat162 h2 = *reinterpret_cast<__hip_bfloat162*>(&hv);
    wsum += w;
    a0 += w * bf2f(h2.x);
    a1 += w * bf2f(h2.y);
  }
  float inv = 1.f/(wsum + 1e-16f);
  unsigned short o0 = f2bf(fmaxf(a0*inv, 0.f));   // relu fused
  unsigned short o1 = f2bf(fmaxf(a1*inv, 0.f));
  unsigned int pk = (unsigned int)o0 | ((unsigned int)o1 << 16);
  *reinterpret_cast<unsigned int*>(outs + ((size_t)p*NN + dst)*NC + lane*2) = pk;
}

// ---------------------------------------------------------------- semantic att: wsum[p,c] = sum_n tanh(outs@kW + kb)
// outs is bf16 (pre-relu'd): staging is pure 16B copies, no cvt.
__global__ __launch_bounds__(256) void k_semantic(const __hip_bfloat16* __restrict__ outs,
      const float* __restrict__ kW, const float* __restrict__ kb,
      float* __restrict__ wsum){
  __shared__ __align__(16) __hip_bfloat16 As[64*40];
  __shared__ __align__(16) __hip_bfloat16 Bs[128*136];  // whole kW^T, bf16, pad 136
  __shared__ float wsum_s[NC];
  const int tid = threadIdx.x;
  const int wave = tid >> 6, lane = tid & 63;
  const int lr = lane & 15, lq = lane >> 4;
  const int p = blockIdx.y;
  const __hip_bfloat16* op = outs + (size_t)p*NN*NC;
  for (int i=tid; i<NC*NC; i+=256){
    int k = i >> 7, c = i & 127;
    Bs[c*136 + k] = __float2bfloat16(kW[i]);
  }
  if (tid < NC) wsum_s[tid] = 0.f;
  float kbv[8];
#pragma unroll
  for (int t=0;t<8;t++) kbv[t] = kb[t*16 + lr];
  float ps[8] = {};
  const int ntiles = (NN + 63)/64;
  for (int tile = blockIdx.x; tile < ntiles; tile += gridDim.x){
    const int m0 = tile*64;
    f32x4 acc[8] = {};
    for (int k0=0; k0<NC; k0+=32){
      {
        int row = tid >> 2, q = tid & 3;   // 64 rows x 32 k, 16B per thread
        int gm = m0 + row; if (gm >= NN) gm = NN-1;
        const uint4 v = *reinterpret_cast<const uint4*>(op + (size_t)gm*NC + k0 + q*8);
        *reinterpret_cast<uint4*>(&As[row*40 + q*8]) = v;
      }
      __syncthreads();   // also covers one-time Bs/wsum_s staging on first iter
      bf16x8 afr = *reinterpret_cast<const bf16x8*>(&As[(wave*16 + lr)*40 + lq*8]);
#pragma unroll
      for (int t=0;t<8;t++){
        bf16x8 bfr = *reinterpret_cast<const bf16x8*>(&Bs[(t*16 + lr)*136 + k0 + lq*8]);
        acc[t] = __builtin_amdgcn_mfma_f32_16x16x32_bf16(afr, bfr, acc[t], 0, 0, 0);
      }
      __syncthreads();
    }
#pragma unroll
    for (int t=0;t<8;t++){
#pragma unroll
      for (int r=0;r<4;r++){
        int gm = m0 + wave*16 + lq*4 + r;
        if (gm < NN) ps[t] += tanh_fast(acc[t][r] + kbv[t]);
      }
    }
  }
#pragma unroll
  for (int t=0;t<8;t++) atomicAdd(&wsum_s[t*16 + lr], ps[t]);
  __syncthreads();
  if (tid < NC) atomicAdd(&wsum[p*NC + tid], wsum_s[tid]);
}

// ---------------------------------------------------------------- beta = softmax(q . mean_tanh)
__global__ void k_beta(const float* __restrict__ wsum, const float* __restrict__ qv,
                       float* __restrict__ beta){
  int lane = threadIdx.x;  // 64 threads
  float s[NP];
#pragma unroll
  for (int p=0;p<NP;p++){
    float acc = wsum[p*NC + lane]*qv[lane] + wsum[p*NC + lane + 64]*qv[lane + 64];
#pragma unroll
    for (int off=32; off>0; off>>=1) acc += __shfl_down(acc, off);
    s[p] = acc;
  }
  if (lane == 0){
    float sc0 = s[0]/(float)NN, sc1 = s[1]/(float)NN, sc2 = s[2]/(float)NN;
    float mx = fmaxf(sc0, fmaxf(sc1, sc2));
    float e0 = __expf(sc0-mx), e1 = __expf(sc1-mx), e2 = __expf(sc2-mx);
    float inv = 1.0f/(e0+e1+e2);
    beta[0]=e0*inv; beta[1]=e1*inv; beta[2]=e2*inv;
  }
}

// ---------------------------------------------------------------- fused = sum_p beta_p outs_p; out = fused@linW + linb
__global__ __launch_bounds__(256) void k_fuse(const __hip_bfloat16* __restrict__ outs,
      const float* __restrict__ beta, const float* __restrict__ linW,
      const float* __restrict__ linb, float* __restrict__ out){
  int node = blockIdx.x*4 + (threadIdx.x >> 6);
  int lane = threadIdx.x & 63;
  if (node >= NN) return;
  float b0 = beta[0], b1 = beta[1], b2 = beta[2];
  unsigned int u0 = *reinterpret_cast<const unsigned int*>(outs + ((size_t)0*NN+node)*NC + lane*2);
  unsigned int u1 = *reinterpret_cast<const unsigned int*>(outs + ((size_t)1*NN+node)*NC + lane*2);
  unsigned int u2 = *reinterpret_cast<const unsigned int*>(outs + ((size_t)2*NN+node)*NC + lane*2);
  __hip_bfloat162 v0 = *reinterpret_cast<__hip_bfloat162*>(&u0);
  __hip_bfloat162 v1 = *reinterpret_cast<__hip_bfloat162*>(&u1);
  __hip_bfloat162 v2 = *reinterpret_cast<__hip_bfloat162*>(&u2);
  float f0 = b0*bf2f(v0.x) + b1*bf2f(v1.x) + b2*bf2f(v2.x);
  float f1 = b0*bf2f(v0.y) + b1*bf2f(v1.y) + b2*bf2f(v2.y);
  int c0 = lane*2, c1 = lane*2 + 1;
  float a0 = f0*linW[c0*NOUT+0] + f1*linW[c1*NOUT+0];
  float a1 = f0*linW[c0*NOUT+1] + f1*linW[c1*NOUT+1];
  float a2 = f0*linW[c0*NOUT+2] + f1*linW[c1*NOUT+2];
#pragma unroll
  for (int off=32; off>0; off>>=1){
    a0 += __shfl_down(a0, off);
    a1 += __shfl_down(a1, off);
    a2 += __shfl_down(a2, off);
  }
  if (lane == 0){
    out[(size_t)node*NOUT + 0] = a0 + linb[0];
    out[(size_t)node*NOUT + 1] = a1 + linb[1];
    out[(size_t)node*NOUT + 2] = a2 + linb[2];
  }
}

extern "C" void kernel_launch(void* const* d_in, const int* in_sizes, int n_in,
                              void* d_out, int out_size, void* d_ws, size_t ws_size,
                              hipStream_t stream){
  const float* x     = (const float*)d_in[0];
  const int*   edge  = (const int*)d_in[1];
  const float* Wp    = (const float*)d_in[2];
  const float* bp    = (const float*)d_in[3];
  const float* a_src = (const float*)d_in[4];
  const float* a_dst = (const float*)d_in[5];
  const float* kW    = (const float*)d_in[6];
  const float* kb    = (const float*)d_in[7];
  const float* qv    = (const float*)d_in[8];
  const float* linW  = (const float*)d_in[9];
  const float* linb  = (const float*)d_in[10];
  float* out = (float*)d_out;
  char* ws = (char*)d_ws;

  // workspace layout (bytes), total ~131.5 MB (outs now bf16)
  __hip_bfloat16* Wt  = (__hip_bfloat16*)(ws + 0);           //    262,144
  __hip_bfloat16* h   = (__hip_bfloat16*)(ws + 262144);      // 25,600,000
  float* al_s   = (float*)(ws + 25862144);                   //  9,600,000
  float* al_d   = (float*)(ws + 35462144);                   //  9,600,000
  int* deg      = (int*)(ws + 45062144);                     //  1,200,000 (reused as cursor)
  int* row_start= (int*)(ws + 46262144);                     //  1,200,016
  int* blksum   = (int*)(ws + 47462160);                     //      1,536
  int* csr_src  = (int*)(ws + 47463696);                     //  7,200,000
  __hip_bfloat16* outs = (__hip_bfloat16*)(ws + 54663696);   // 76,800,000
  float* wsum   = (float*)(ws + 131463696);                  //      1,536
  float* beta   = (float*)(ws + 131465232);                  //         12
  int* cursor   = deg;                                       // alias: deg dead after scan

  hipMemsetAsync(deg,  0, (size_t)NP*NN*4, stream);
  hipMemsetAsync(wsum, 0, NP*NC*4, stream);

  k_transpose_w<<<(FIN*NC + 255)/256, 256, 0, stream>>>(Wp, Wt);
  k_proj<<<(NN + 63)/64, 256, 0, stream>>>(x, Wt, bp, h);
  k_al<<<(NN*NH + 255)/256, 256, 0, stream>>>(h, a_src, a_dst, al_s, al_d);
  k_deg<<<dim3((NE + 255)/256, NP), 256, 0, stream>>>(edge, deg);
  k_scan_blk<<<dim3(NBLK, NP), 256, 0, stream>>>(deg, row_start, blksum);
  k_scan_top<<<NP, 128, 0, stream>>>(blksum);
  k_scan_add<<<dim3(NBLK, NP), 256, 0, stream>>>(row_start, blksum, cursor);
  k_fill<<<dim3((NE + 255)/256, NP), 256, 0, stream>>>(edge, cursor, csr_src);
  k_gather<<<dim3((NN + 3)/4, NP), 256, 0, stream>>>(row_start, csr_src, h, al_s, al_d, outs);
  k_semantic<<<dim3(256, NP), 256, 0, stream>>>(outs, kW, kb, wsum);
  k_beta<<<1, 64, 0, stream>>>(wsum, qv, beta);
  k_fuse<<<(NN + 3)/4, 256, 0, stream>>>(outs, beta, linW, linb, out);
}